// Round 1
// baseline (1074.203 us; speedup 1.0000x reference)
//
#include <hip/hip_runtime.h>
#include <math.h>

// Shapes (fixed for this problem)
#define BATCH 2
#define NTOK 4096        // H*W = 64*64
#define CDIM 256
#define NH 8
#define HD 32
#define MROWS (BATCH * NTOK)   // 8192

// ---------------- QKV projection GEMM ----------------
// X [8192][256] * Wqkv [256][768] + bqkv -> scatter into Q/K/V [b][h][n][e]
#define BM 64
#define BN 64
#define BK 64

__global__ __launch_bounds__(256) void qkv_gemm(
    const float* __restrict__ X, const float* __restrict__ W,
    const float* __restrict__ bias,
    float* __restrict__ Qb, float* __restrict__ Kb, float* __restrict__ Vb)
{
    __shared__ float As[BK][BM + 4];   // As[k][m], row stride 68 floats (16B aligned)
    __shared__ float Bs[BK][BN + 4];

    const int tid = threadIdx.x;
    const int tx = tid & 15;          // 0..15 (cols)
    const int ty = tid >> 4;          // 0..15 (rows)
    const int row0 = blockIdx.x * BM;
    const int col0 = blockIdx.y * BN;

    float c[4][4] = {};

    for (int k0 = 0; k0 < CDIM; k0 += BK) {
        // Load A tile (64 rows x 64 k), store transposed As[k][m]
        #pragma unroll
        for (int i = 0; i < 4; ++i) {
            int l = tid + i * 256;        // 0..1023
            int r = l >> 4;               // row in tile
            int k4 = (l & 15) << 2;       // k offset
            float4 v = *(const float4*)&X[(size_t)(row0 + r) * CDIM + k0 + k4];
            As[k4 + 0][r] = v.x;
            As[k4 + 1][r] = v.y;
            As[k4 + 2][r] = v.z;
            As[k4 + 3][r] = v.w;
        }
        // Load B tile (64 k x 64 cols), natural layout
        #pragma unroll
        for (int i = 0; i < 4; ++i) {
            int l = tid + i * 256;
            int r = l >> 4;               // k row
            int c4 = (l & 15) << 2;
            *(float4*)&Bs[r][c4] = *(const float4*)&W[(size_t)(k0 + r) * 768 + col0 + c4];
        }
        __syncthreads();

        #pragma unroll 16
        for (int kk = 0; kk < BK; ++kk) {
            float4 a = *(const float4*)&As[kk][ty << 2];
            float4 b = *(const float4*)&Bs[kk][tx << 2];
            float av[4] = {a.x, a.y, a.z, a.w};
            float bv[4] = {b.x, b.y, b.z, b.w};
            #pragma unroll
            for (int i = 0; i < 4; ++i)
                #pragma unroll
                for (int j = 0; j < 4; ++j)
                    c[i][j] = fmaf(av[i], bv[j], c[i][j]);
        }
        __syncthreads();
    }

    // Epilogue: bias + scatter into Q/K/V with layout [b][h][n][e]
    #pragma unroll
    for (int i = 0; i < 4; ++i) {
        int gr = row0 + (ty << 2) + i;     // global row in [0, 8192)
        int b_ = gr >> 12;                 // batch
        int n  = gr & (NTOK - 1);
        #pragma unroll
        for (int j = 0; j < 4; ++j) {
            int gc = col0 + (tx << 2) + j; // global col in [0, 768)
            float val = c[i][j] + bias[gc];
            int s  = gc >> 8;              // 0=Q 1=K 2=V
            int hd = gc & 255;
            int h  = hd >> 5;
            int e  = hd & 31;
            float* dst = (s == 0) ? Qb : (s == 1) ? Kb : Vb;
            dst[(((size_t)(b_ * NH + h)) * NTOK + n) * HD + e] = val;
        }
    }
}

// ---------------- Flash attention (fp32, thread-per-q-row) ----------------
// rel_bias is a per-head scalar added uniformly to every logit in a row:
// softmax(s + c) == softmax(s), so it is mathematically a no-op and dropped.
__global__ __launch_bounds__(256) void attn_kernel(
    const float* __restrict__ Qb, const float* __restrict__ Kb,
    const float* __restrict__ Vb, float* __restrict__ AO)
{
    const int b = blockIdx.z;
    const int h = blockIdx.y;
    const int n = blockIdx.x * 256 + threadIdx.x;
    const size_t hb = ((size_t)(b * NH + h)) * NTOK * HD;

    // q row in registers
    float4 q4[8];
    {
        const float4* qp = (const float4*)(Qb + hb + (size_t)n * HD);
        #pragma unroll
        for (int i = 0; i < 8; ++i) q4[i] = qp[i];
    }

    float acc[HD];
    #pragma unroll
    for (int d = 0; d < HD; ++d) acc[d] = 0.f;
    float m = -INFINITY, l = 0.f;

    __shared__ float Ks[32][36];   // pad 4 -> row 144B (16B aligned), staggers banks
    __shared__ float Vs[32][36];

    const float scale = 0.17677669529663687f;  // 1/sqrt(32)

    for (int kv0 = 0; kv0 < NTOK; kv0 += 32) {
        // Stage K/V tile: 32 rows x 32 floats each; 256 threads -> 1 float4 each
        {
            int r  = threadIdx.x >> 3;
            int c4 = (threadIdx.x & 7) << 2;
            *(float4*)&Ks[r][c4] = *(const float4*)&Kb[hb + (size_t)(kv0 + r) * HD + c4];
            *(float4*)&Vs[r][c4] = *(const float4*)&Vb[hb + (size_t)(kv0 + r) * HD + c4];
        }
        __syncthreads();

        float s[32];
        float mt = m;
        #pragma unroll
        for (int j = 0; j < 32; ++j) {
            float sj = 0.f;
            #pragma unroll
            for (int d4 = 0; d4 < 8; ++d4) {
                float4 kk = *(const float4*)&Ks[j][d4 << 2];
                sj = fmaf(q4[d4].x, kk.x, sj);
                sj = fmaf(q4[d4].y, kk.y, sj);
                sj = fmaf(q4[d4].z, kk.z, sj);
                sj = fmaf(q4[d4].w, kk.w, sj);
            }
            sj *= scale;
            s[j] = sj;
            mt = fmaxf(mt, sj);
        }

        // rescale old state (exp(-inf - mt) = 0 handles first tile)
        float r = __expf(m - mt);
        l *= r;
        #pragma unroll
        for (int d = 0; d < HD; ++d) acc[d] *= r;

        #pragma unroll
        for (int j = 0; j < 32; ++j) {
            float p = __expf(s[j] - mt);
            l += p;
            #pragma unroll
            for (int d4 = 0; d4 < 8; ++d4) {
                float4 vv = *(const float4*)&Vs[j][d4 << 2];
                acc[(d4 << 2) + 0] = fmaf(p, vv.x, acc[(d4 << 2) + 0]);
                acc[(d4 << 2) + 1] = fmaf(p, vv.y, acc[(d4 << 2) + 1]);
                acc[(d4 << 2) + 2] = fmaf(p, vv.z, acc[(d4 << 2) + 2]);
                acc[(d4 << 2) + 3] = fmaf(p, vv.w, acc[(d4 << 2) + 3]);
            }
        }
        m = mt;
        __syncthreads();
    }

    // write AO [b][n][h*32+e]  (i.e. [B][N][C])
    float inv = 1.0f / l;
    float* op = AO + ((size_t)(b * NTOK + n)) * CDIM + h * HD;
    #pragma unroll
    for (int d4 = 0; d4 < 8; ++d4) {
        float4 o;
        o.x = acc[(d4 << 2) + 0] * inv;
        o.y = acc[(d4 << 2) + 1] * inv;
        o.z = acc[(d4 << 2) + 2] * inv;
        o.w = acc[(d4 << 2) + 3] * inv;
        *(float4*)&op[d4 << 2] = o;
    }
}

// ---------------- Output projection GEMM ----------------
// AO [8192][256] * Wp [256][256] + bp -> out [8192][256]
__global__ __launch_bounds__(256) void proj_gemm(
    const float* __restrict__ A, const float* __restrict__ W,
    const float* __restrict__ bias, float* __restrict__ out)
{
    __shared__ float As[BK][BM + 4];
    __shared__ float Bs[BK][BN + 4];

    const int tid = threadIdx.x;
    const int tx = tid & 15;
    const int ty = tid >> 4;
    const int row0 = blockIdx.x * BM;
    const int col0 = blockIdx.y * BN;

    float c[4][4] = {};

    for (int k0 = 0; k0 < CDIM; k0 += BK) {
        #pragma unroll
        for (int i = 0; i < 4; ++i) {
            int l = tid + i * 256;
            int r = l >> 4;
            int k4 = (l & 15) << 2;
            float4 v = *(const float4*)&A[(size_t)(row0 + r) * CDIM + k0 + k4];
            As[k4 + 0][r] = v.x;
            As[k4 + 1][r] = v.y;
            As[k4 + 2][r] = v.z;
            As[k4 + 3][r] = v.w;
        }
        #pragma unroll
        for (int i = 0; i < 4; ++i) {
            int l = tid + i * 256;
            int r = l >> 4;
            int c4 = (l & 15) << 2;
            *(float4*)&Bs[r][c4] = *(const float4*)&W[(size_t)(k0 + r) * CDIM + col0 + c4];
        }
        __syncthreads();

        #pragma unroll 16
        for (int kk = 0; kk < BK; ++kk) {
            float4 a = *(const float4*)&As[kk][ty << 2];
            float4 b = *(const float4*)&Bs[kk][tx << 2];
            float av[4] = {a.x, a.y, a.z, a.w};
            float bv[4] = {b.x, b.y, b.z, b.w};
            #pragma unroll
            for (int i = 0; i < 4; ++i)
                #pragma unroll
                for (int j = 0; j < 4; ++j)
                    c[i][j] = fmaf(av[i], bv[j], c[i][j]);
        }
        __syncthreads();
    }

    #pragma unroll
    for (int i = 0; i < 4; ++i) {
        int gr = row0 + (ty << 2) + i;
        #pragma unroll
        for (int j = 0; j < 4; ++j) {
            int gc = col0 + (tx << 2) + j;
            out[(size_t)gr * CDIM + gc] = c[i][j] + bias[gc];
        }
    }
}

extern "C" void kernel_launch(void* const* d_in, const int* in_sizes, int n_in,
                              void* d_out, int out_size, void* d_ws, size_t ws_size,
                              hipStream_t stream)
{
    const float* x      = (const float*)d_in[0];   // [2,64,64,256]
    const float* w_qkv  = (const float*)d_in[1];   // [256,768]
    const float* b_qkv  = (const float*)d_in[2];   // [768]
    const float* w_proj = (const float*)d_in[3];   // [256,256]
    const float* b_proj = (const float*)d_in[4];   // [256]
    // d_in[5] = rel_bias: per-head scalar over full NxN -> softmax-invariant, dropped.

    float* out = (float*)d_out;

    // Workspace layout (floats): Q, K, V, AO each B*NH*NTOK*HD = 2,097,152 floats
    const size_t BUF = (size_t)BATCH * NH * NTOK * HD;  // 2,097,152
    float* Qb = (float*)d_ws;
    float* Kb = Qb + BUF;
    float* Vb = Kb + BUF;
    float* AO = Vb + BUF;

    // 1) QKV projection
    {
        dim3 grid(MROWS / BM, 768 / BN);   // 128 x 12
        qkv_gemm<<<grid, 256, 0, stream>>>(x, w_qkv, b_qkv, Qb, Kb, Vb);
    }
    // 2) Attention
    {
        dim3 grid(NTOK / 256, NH, BATCH);  // 16 x 8 x 2
        attn_kernel<<<grid, 256, 0, stream>>>(Qb, Kb, Vb, AO);
    }
    // 3) Output projection
    {
        dim3 grid(MROWS / BM, CDIM / BN);  // 128 x 4
        proj_gemm<<<grid, 256, 0, stream>>>(AO, w_proj, b_proj, out);
    }
}

// Round 2
// 284.066 us; speedup vs baseline: 3.7815x; 3.7815x over previous
//
#include <hip/hip_runtime.h>
#include <math.h>

#define BATCH 2
#define NTOK 4096        // H*W
#define CDIM 256
#define NH 8
#define HD 32
#define MROWS (BATCH * NTOK)   // 8192

typedef __attribute__((ext_vector_type(8))) short bf16x8;
typedef __attribute__((ext_vector_type(4))) float f32x4;

__device__ __forceinline__ unsigned short f2bf(float f) {
    union { float f; unsigned u; } x; x.f = f;
    unsigned r = x.u + 0x7FFFu + ((x.u >> 16) & 1u);   // round-to-nearest-even
    return (unsigned short)(r >> 16);
}
__device__ __forceinline__ float bf2f(unsigned short h) {
    union { unsigned u; float f; } x; x.u = ((unsigned)h) << 16; return x.f;
}

// ---------------- QKV projection GEMM ----------------
// X [8192][256] * Wqkv [256][768] + b ->
//   Q fp32 [bh][n][32], K bf16 hi/lo [bh][n][32], V bf16 hi/lo [bh][32][n] (transposed)
#define BM 64
#define BN 64
#define BK 64

__global__ __launch_bounds__(256) void qkv_gemm(
    const float* __restrict__ X, const float* __restrict__ W,
    const float* __restrict__ bias,
    float* __restrict__ Qb,
    unsigned short* __restrict__ Khi, unsigned short* __restrict__ Klo,
    unsigned short* __restrict__ Vhi, unsigned short* __restrict__ Vlo)
{
    __shared__ float As[BK][BM + 4];
    __shared__ float Bs[BK][BN + 4];

    const int tid = threadIdx.x;
    const int tx = tid & 15;
    const int ty = tid >> 4;
    const int row0 = blockIdx.x * BM;
    const int col0 = blockIdx.y * BN;

    float c[4][4] = {};

    for (int k0 = 0; k0 < CDIM; k0 += BK) {
        #pragma unroll
        for (int i = 0; i < 4; ++i) {
            int l = tid + i * 256;
            int r = l >> 4;
            int k4 = (l & 15) << 2;
            float4 v = *(const float4*)&X[(size_t)(row0 + r) * CDIM + k0 + k4];
            As[k4 + 0][r] = v.x; As[k4 + 1][r] = v.y;
            As[k4 + 2][r] = v.z; As[k4 + 3][r] = v.w;
        }
        #pragma unroll
        for (int i = 0; i < 4; ++i) {
            int l = tid + i * 256;
            int r = l >> 4;
            int c4 = (l & 15) << 2;
            *(float4*)&Bs[r][c4] = *(const float4*)&W[(size_t)(k0 + r) * 768 + col0 + c4];
        }
        __syncthreads();

        #pragma unroll 16
        for (int kk = 0; kk < BK; ++kk) {
            float4 a = *(const float4*)&As[kk][ty << 2];
            float4 b = *(const float4*)&Bs[kk][tx << 2];
            float av[4] = {a.x, a.y, a.z, a.w};
            float bv[4] = {b.x, b.y, b.z, b.w};
            #pragma unroll
            for (int i = 0; i < 4; ++i)
                #pragma unroll
                for (int j = 0; j < 4; ++j)
                    c[i][j] = fmaf(av[i], bv[j], c[i][j]);
        }
        __syncthreads();
    }

    // Epilogue: whole block is within one of Q/K/V (col0 multiple of 64, groups of 256)
    const int s = col0 >> 8;            // 0=Q 1=K 2=V
    const int b_ = row0 >> 12;          // batch (block rows never straddle)
    const int n0 = (row0 & (NTOK - 1)) + (ty << 2);
    const int gc0 = col0 + (tx << 2);
    const int h  = (gc0 >> 5) & 7;
    const int e0 = gc0 & 31;
    const int bh = b_ * NH + h;

    if (s == 0) {
        #pragma unroll
        for (int i = 0; i < 4; ++i) {
            float4 o;
            o.x = c[i][0] + bias[gc0 + 0];
            o.y = c[i][1] + bias[gc0 + 1];
            o.z = c[i][2] + bias[gc0 + 2];
            o.w = c[i][3] + bias[gc0 + 3];
            *(float4*)&Qb[((size_t)bh * NTOK + n0 + i) * HD + e0] = o;
        }
    } else if (s == 1) {
        #pragma unroll
        for (int i = 0; i < 4; ++i) {
            unsigned short hh[4], ll[4];
            #pragma unroll
            for (int j = 0; j < 4; ++j) {
                float v = c[i][j] + bias[gc0 + j];
                hh[j] = f2bf(v);
                ll[j] = f2bf(v - bf2f(hh[j]));
            }
            size_t idx = ((size_t)bh * NTOK + n0 + i) * HD + e0;
            uint2 hw; hw.x = hh[0] | ((unsigned)hh[1] << 16); hw.y = hh[2] | ((unsigned)hh[3] << 16);
            uint2 lw; lw.x = ll[0] | ((unsigned)ll[1] << 16); lw.y = ll[2] | ((unsigned)ll[3] << 16);
            *(uint2*)&Khi[idx] = hw;
            *(uint2*)&Klo[idx] = lw;
        }
    } else {
        // V transposed: [bh][e][n]
        #pragma unroll
        for (int j = 0; j < 4; ++j) {
            unsigned short hh[4], ll[4];
            #pragma unroll
            for (int i = 0; i < 4; ++i) {
                float v = c[i][j] + bias[gc0 + j];
                hh[i] = f2bf(v);
                ll[i] = f2bf(v - bf2f(hh[i]));
            }
            size_t idx = ((size_t)bh * HD + e0 + j) * NTOK + n0;
            uint2 hw; hw.x = hh[0] | ((unsigned)hh[1] << 16); hw.y = hh[2] | ((unsigned)hh[3] << 16);
            uint2 lw; lw.x = ll[0] | ((unsigned)ll[1] << 16); lw.y = ll[2] | ((unsigned)ll[3] << 16);
            *(uint2*)&Vhi[idx] = hw;
            *(uint2*)&Vlo[idx] = lw;
        }
    }
}

// ---------------- MFMA flash attention ----------------
// Swapped QK^T: S^T = K * Q^T via mfma(A=K, B=Q^T). C layout: col=lane&15 (q),
// row=(lane>>4)*4+reg (kv). PV: O^T = V^T * P^T with A=V^T (staged transposed),
// B=P^T read from per-wave LDS P buffer stored as P[q][kv].
// Split-bf16: x = hi + lo; x*y ~= xh*yh + xh*yl + xl*yh (3 MFMAs).
__global__ __launch_bounds__(256) void attn_mfma(
    const float* __restrict__ Q,
    const unsigned short* __restrict__ Khi, const unsigned short* __restrict__ Klo,
    const unsigned short* __restrict__ Vhi, const unsigned short* __restrict__ Vlo,
    float* __restrict__ AO)
{
    __shared__ __align__(16) unsigned short KsH[64][40], KsL[64][40];   // pitch 80B
    __shared__ __align__(16) unsigned short VsH[32][72], VsL[32][72];   // pitch 144B
    __shared__ __align__(16) unsigned short Pb[4][2][2][16][72];        // [wave][qt][hi/lo][q][kv]

    const int tid = threadIdx.x;
    const int w  = tid >> 6;
    const int l  = tid & 63;
    const int lq = l & 15;
    const int g  = l >> 4;
    const int bh = blockIdx.y;
    const int q0 = blockIdx.x * 128 + w * 32;
    const int kb = bh * (NTOK * HD);
    const int vb = bh * (HD * NTOK);

    const float scale = 0.17677669529663687f;  // 1/sqrt(32), folded into Q

    // Q fragments (B operand: B[k][col]; lane needs Q[q0+qt*16+lq][8g+j])
    bf16x8 qh[2], ql[2];
    #pragma unroll
    for (int qt = 0; qt < 2; ++qt) {
        const float* qp = Q + kb + (q0 + qt * 16 + lq) * HD + g * 8;
        float4 qa = *(const float4*)qp;
        float4 qb2 = *(const float4*)(qp + 4);
        float f[8] = {qa.x, qa.y, qa.z, qa.w, qb2.x, qb2.y, qb2.z, qb2.w};
        #pragma unroll
        for (int j = 0; j < 8; ++j) {
            float v = f[j] * scale;
            unsigned short hh = f2bf(v);
            qh[qt][j] = (short)hh;
            ql[qt][j] = (short)f2bf(v - bf2f(hh));
        }
    }

    f32x4 o[2][2] = {};                 // [qt][mt] : O^T accum (d = 16*mt + 4g + reg)
    float m[2] = {-1e30f, -1e30f};
    float lsum[2] = {0.f, 0.f};

    for (int kv0 = 0; kv0 < NTOK; kv0 += 64) {
        // ---- stage K (64x32) and V^T (32x64), bf16 hi/lo, 16B per thread each ----
        {
            int r  = tid >> 2, ch = (tid & 3) << 3;
            int gi = kb + (kv0 + r) * HD + ch;
            *(uint4*)&KsH[r][ch] = *(const uint4*)&Khi[gi];
            *(uint4*)&KsL[r][ch] = *(const uint4*)&Klo[gi];
            int r2 = tid >> 3, ch2 = (tid & 7) << 3;
            int gi2 = vb + r2 * NTOK + kv0 + ch2;
            *(uint4*)&VsH[r2][ch2] = *(const uint4*)&Vhi[gi2];
            *(uint4*)&VsL[r2][ch2] = *(const uint4*)&Vlo[gi2];
        }
        __syncthreads();

        // ---- fragments from LDS ----
        bf16x8 kh[4], kl[4];
        #pragma unroll
        for (int t = 0; t < 4; ++t) {
            kh[t] = *(const bf16x8*)&KsH[16 * t + lq][g * 8];
            kl[t] = *(const bf16x8*)&KsL[16 * t + lq][g * 8];
        }
        bf16x8 vh[2][2], vl[2][2];
        #pragma unroll
        for (int mt = 0; mt < 2; ++mt)
            #pragma unroll
            for (int ks = 0; ks < 2; ++ks) {
                vh[mt][ks] = *(const bf16x8*)&VsH[16 * mt + lq][ks * 32 + g * 8];
                vl[mt][ks] = *(const bf16x8*)&VsL[16 * mt + lq][ks * 32 + g * 8];
            }

        // ---- QK^T + online softmax + P pack, per q-tile ----
        #pragma unroll
        for (int qt = 0; qt < 2; ++qt) {
            f32x4 sc[4];
            #pragma unroll
            for (int t = 0; t < 4; ++t) {
                f32x4 c = {0.f, 0.f, 0.f, 0.f};
                c = __builtin_amdgcn_mfma_f32_16x16x32_bf16(kh[t], qh[qt], c, 0, 0, 0);
                c = __builtin_amdgcn_mfma_f32_16x16x32_bf16(kh[t], ql[qt], c, 0, 0, 0);
                c = __builtin_amdgcn_mfma_f32_16x16x32_bf16(kl[t], qh[qt], c, 0, 0, 0);
                sc[t] = c;
            }
            float mloc = -1e30f;
            #pragma unroll
            for (int t = 0; t < 4; ++t) {
                mloc = fmaxf(mloc, fmaxf(fmaxf(sc[t][0], sc[t][1]), fmaxf(sc[t][2], sc[t][3])));
            }
            mloc = fmaxf(mloc, __shfl_xor(mloc, 16));
            mloc = fmaxf(mloc, __shfl_xor(mloc, 32));
            float mnew = fmaxf(m[qt], mloc);
            float rs = __expf(m[qt] - mnew);
            m[qt] = mnew;
            lsum[qt] *= rs;
            #pragma unroll
            for (int mt = 0; mt < 2; ++mt) {
                o[qt][mt][0] *= rs; o[qt][mt][1] *= rs;
                o[qt][mt][2] *= rs; o[qt][mt][3] *= rs;
            }
            #pragma unroll
            for (int t = 0; t < 4; ++t) {
                float p0 = __expf(sc[t][0] - mnew);
                float p1 = __expf(sc[t][1] - mnew);
                float p2 = __expf(sc[t][2] - mnew);
                float p3 = __expf(sc[t][3] - mnew);
                lsum[qt] += (p0 + p1) + (p2 + p3);
                unsigned short h0 = f2bf(p0), h1 = f2bf(p1), h2 = f2bf(p2), h3 = f2bf(p3);
                uint2 hw; hw.x = h0 | ((unsigned)h1 << 16); hw.y = h2 | ((unsigned)h3 << 16);
                *(uint2*)&Pb[w][qt][0][lq][16 * t + 4 * g] = hw;
                unsigned short e0 = f2bf(p0 - bf2f(h0)), e1 = f2bf(p1 - bf2f(h1));
                unsigned short e2 = f2bf(p2 - bf2f(h2)), e3 = f2bf(p3 - bf2f(h3));
                uint2 lw; lw.x = e0 | ((unsigned)e1 << 16); lw.y = e2 | ((unsigned)e3 << 16);
                *(uint2*)&Pb[w][qt][1][lq][16 * t + 4 * g] = lw;
            }
        }

        // same-wave cross-lane LDS dependency: drain DS queue
        asm volatile("s_waitcnt lgkmcnt(0)" ::: "memory");

        // ---- PV: O^T += V^T * P^T ----
        #pragma unroll
        for (int qt = 0; qt < 2; ++qt) {
            #pragma unroll
            for (int ks = 0; ks < 2; ++ks) {
                bf16x8 ph = *(const bf16x8*)&Pb[w][qt][0][lq][ks * 32 + g * 8];
                bf16x8 pl = *(const bf16x8*)&Pb[w][qt][1][lq][ks * 32 + g * 8];
                #pragma unroll
                for (int mt = 0; mt < 2; ++mt) {
                    o[qt][mt] = __builtin_amdgcn_mfma_f32_16x16x32_bf16(vh[mt][ks], ph, o[qt][mt], 0, 0, 0);
                    o[qt][mt] = __builtin_amdgcn_mfma_f32_16x16x32_bf16(vh[mt][ks], pl, o[qt][mt], 0, 0, 0);
                    o[qt][mt] = __builtin_amdgcn_mfma_f32_16x16x32_bf16(vl[mt][ks], ph, o[qt][mt], 0, 0, 0);
                }
            }
        }
        __syncthreads();
    }

    // ---- finalize: reduce l across groups, scale, store ----
    const int b_ = bh >> 3, h_ = bh & 7;
    #pragma unroll
    for (int qt = 0; qt < 2; ++qt) {
        float ls = lsum[qt];
        ls += __shfl_xor(ls, 16);
        ls += __shfl_xor(ls, 32);
        float inv = 1.0f / ls;
        int qg = q0 + qt * 16 + lq;
        #pragma unroll
        for (int mt = 0; mt < 2; ++mt) {
            float4 st;
            st.x = o[qt][mt][0] * inv;
            st.y = o[qt][mt][1] * inv;
            st.z = o[qt][mt][2] * inv;
            st.w = o[qt][mt][3] * inv;
            *(float4*)&AO[((size_t)b_ * NTOK + qg) * CDIM + h_ * 32 + mt * 16 + g * 4] = st;
        }
    }
}

// ---------------- Output projection GEMM ----------------
__global__ __launch_bounds__(256) void proj_gemm(
    const float* __restrict__ A, const float* __restrict__ W,
    const float* __restrict__ bias, float* __restrict__ out)
{
    __shared__ float As[BK][BM + 4];
    __shared__ float Bs[BK][BN + 4];

    const int tid = threadIdx.x;
    const int tx = tid & 15;
    const int ty = tid >> 4;
    const int row0 = blockIdx.x * BM;
    const int col0 = blockIdx.y * BN;

    float c[4][4] = {};

    for (int k0 = 0; k0 < CDIM; k0 += BK) {
        #pragma unroll
        for (int i = 0; i < 4; ++i) {
            int l = tid + i * 256;
            int r = l >> 4;
            int k4 = (l & 15) << 2;
            float4 v = *(const float4*)&A[(size_t)(row0 + r) * CDIM + k0 + k4];
            As[k4 + 0][r] = v.x; As[k4 + 1][r] = v.y;
            As[k4 + 2][r] = v.z; As[k4 + 3][r] = v.w;
        }
        #pragma unroll
        for (int i = 0; i < 4; ++i) {
            int l = tid + i * 256;
            int r = l >> 4;
            int c4 = (l & 15) << 2;
            *(float4*)&Bs[r][c4] = *(const float4*)&W[(size_t)(k0 + r) * CDIM + col0 + c4];
        }
        __syncthreads();

        #pragma unroll 16
        for (int kk = 0; kk < BK; ++kk) {
            float4 a = *(const float4*)&As[kk][ty << 2];
            float4 b = *(const float4*)&Bs[kk][tx << 2];
            float av[4] = {a.x, a.y, a.z, a.w};
            float bv[4] = {b.x, b.y, b.z, b.w};
            #pragma unroll
            for (int i = 0; i < 4; ++i)
                #pragma unroll
                for (int j = 0; j < 4; ++j)
                    c[i][j] = fmaf(av[i], bv[j], c[i][j]);
        }
        __syncthreads();
    }

    #pragma unroll
    for (int i = 0; i < 4; ++i) {
        int gr = row0 + (ty << 2) + i;
        #pragma unroll
        for (int j = 0; j < 4; ++j) {
            int gc = col0 + (tx << 2) + j;
            out[(size_t)gr * CDIM + gc] = c[i][j] + bias[gc];
        }
    }
}

extern "C" void kernel_launch(void* const* d_in, const int* in_sizes, int n_in,
                              void* d_out, int out_size, void* d_ws, size_t ws_size,
                              hipStream_t stream)
{
    const float* x      = (const float*)d_in[0];
    const float* w_qkv  = (const float*)d_in[1];
    const float* b_qkv  = (const float*)d_in[2];
    const float* w_proj = (const float*)d_in[3];
    const float* b_proj = (const float*)d_in[4];
    // d_in[5] rel_bias: per-head scalar over the full score matrix -> softmax no-op.

    float* out = (float*)d_out;

    // Workspace: Q fp32 8MB | Khi 4MB | Klo 4MB | Vhi 4MB | Vlo 4MB | AO fp32 8MB = 32MB
    const size_t NE = (size_t)BATCH * NH * NTOK * HD;   // 2,097,152 elements
    char* p = (char*)d_ws;
    float* Qb           = (float*)p;            p += NE * 4;
    unsigned short* Khi = (unsigned short*)p;   p += NE * 2;
    unsigned short* Klo = (unsigned short*)p;   p += NE * 2;
    unsigned short* Vhi = (unsigned short*)p;   p += NE * 2;
    unsigned short* Vlo = (unsigned short*)p;   p += NE * 2;
    float* AO           = (float*)p;

    {
        dim3 grid(MROWS / BM, 768 / BN);   // 128 x 12
        qkv_gemm<<<grid, 256, 0, stream>>>(x, w_qkv, b_qkv, Qb, Khi, Klo, Vhi, Vlo);
    }
    {
        dim3 grid(NTOK / 128, BATCH * NH); // 32 x 16
        attn_mfma<<<grid, 256, 0, stream>>>(Qb, Khi, Klo, Vhi, Vlo, AO);
    }
    {
        dim3 grid(MROWS / BM, CDIM / BN);  // 128 x 4
        proj_gemm<<<grid, 256, 0, stream>>>(AO, w_proj, b_proj, out);
    }
}